// Round 1
// baseline (78.504 us; speedup 1.0000x reference)
//
#include <hip/hip_runtime.h>

// out[b] = 0.75 * sum_i x[b,i] * s[i],  s[i] = sum_h W[h,i]
// x: [2048, 8192] f32 ; W: [8192, 8192] f32 ; out: [2048] f32

#define I_SIZE 8192
#define H_SIZE 8192
#define BATCH  2048

// ---- Kernel 1: column sums of W into s[8192] (d_ws) -----------------------
// Grid: (I_SIZE/1024, H_SIZE/ROWS_PER_CHUNK) = (8, 128). Block: 256 threads.
// Each thread owns 4 consecutive columns (float4), accumulates 64 rows in
// registers, then atomically adds its partial into s.
#define ROWS_PER_CHUNK 64

__global__ __launch_bounds__(256) void colsum_kernel(const float* __restrict__ W,
                                                     float* __restrict__ s) {
    const int col = blockIdx.x * 1024 + threadIdx.x * 4;
    const size_t r0 = (size_t)blockIdx.y * ROWS_PER_CHUNK;
    const float* base = W + r0 * I_SIZE + col;

    float4 acc = make_float4(0.f, 0.f, 0.f, 0.f);
#pragma unroll 8
    for (int r = 0; r < ROWS_PER_CHUNK; ++r) {
        float4 v = *reinterpret_cast<const float4*>(base + (size_t)r * I_SIZE);
        acc.x += v.x; acc.y += v.y; acc.z += v.z; acc.w += v.w;
    }
    atomicAdd(&s[col + 0], acc.x);
    atomicAdd(&s[col + 1], acc.y);
    atomicAdd(&s[col + 2], acc.z);
    atomicAdd(&s[col + 3], acc.w);
}

// ---- Kernel 2: out[b] = 0.75 * dot(x[b], s) --------------------------------
// One 256-thread block per batch row. float4 loads; wave shuffle reduce
// (width 64) then tiny LDS reduce across the 4 waves.
__global__ __launch_bounds__(256) void rowdot_kernel(const float* __restrict__ x,
                                                     const float* __restrict__ s,
                                                     float* __restrict__ out) {
    const int b = blockIdx.x;
    const float* xr = x + (size_t)b * I_SIZE;

    float acc = 0.f;
#pragma unroll
    for (int i = threadIdx.x * 4; i < I_SIZE; i += 256 * 4) {
        float4 xv = *reinterpret_cast<const float4*>(xr + i);
        float4 sv = *reinterpret_cast<const float4*>(s + i);
        acc += xv.x * sv.x + xv.y * sv.y + xv.z * sv.z + xv.w * sv.w;
    }

    // wave-64 butterfly reduce
#pragma unroll
    for (int off = 32; off; off >>= 1)
        acc += __shfl_down(acc, off, 64);

    __shared__ float partial[4];
    const int lane = threadIdx.x & 63;
    const int wid  = threadIdx.x >> 6;
    if (lane == 0) partial[wid] = acc;
    __syncthreads();
    if (threadIdx.x == 0)
        out[b] = 0.75f * (partial[0] + partial[1] + partial[2] + partial[3]);
}

extern "C" void kernel_launch(void* const* d_in, const int* in_sizes, int n_in,
                              void* d_out, int out_size, void* d_ws, size_t ws_size,
                              hipStream_t stream) {
    const float* x = (const float*)d_in[0];   // [BATCH, I_SIZE]
    const float* W = (const float*)d_in[1];   // [H_SIZE, I_SIZE]
    float* out = (float*)d_out;               // [BATCH]
    float* s   = (float*)d_ws;                // [I_SIZE] column sums

    // zero the accumulator (graph-capture-safe async memset)
    hipMemsetAsync(s, 0, I_SIZE * sizeof(float), stream);

    dim3 grid1(I_SIZE / 1024, H_SIZE / ROWS_PER_CHUNK);
    colsum_kernel<<<grid1, 256, 0, stream>>>(W, s);

    rowdot_kernel<<<BATCH, 256, 0, stream>>>(x, s, out);
}